// Round 1
// baseline (797.407 us; speedup 1.0000x reference)
//
#include <hip/hip_runtime.h>
#include <math.h>

// Problem constants: B=2, D_e=128, D_o=256, T=16, H=W=64, H_ref=W_ref=32, s=2, k=32
// n_blocks = T*H_ref*W_ref = 16384 per batch; HW_ref = 1024 query blocks per batch.

// ---------------- workspace layout (bytes) ----------------
// [0, 134217728)      : qk_T [2][1024][16384] f32   (later reused as m_out_b [2][16384][4][256])
// [134217728, +64MB)  : m_in_b [2][16384][4][128] f32
// [201326592, +4MB)   : q_b [2][1024][4][128] f32
// [205520896, +256KB) : idx_sorted [2][1024][32] int32
// total ~205.8 MB

// ---------------- kernel 1: transpose qk_ref [B,16384,1024] -> [B,1024,16384] ----------------
__global__ __launch_bounds__(256) void transpose_qk(const float* __restrict__ in,
                                                    float* __restrict__ out) {
    __shared__ float tile[64][65];
    int r0 = blockIdx.x * 64;          // row tile (16384 dim)
    int q0 = blockIdx.y * 64;          // col tile (1024 dim)
    int b  = blockIdx.z;
    const float* src = in  + (size_t)b * 16384 * 1024;
    float*       dst = out + (size_t)b * 1024 * 16384;
    int tx = threadIdx.x & 63;
    int ty = threadIdx.x >> 6;         // 0..3
#pragma unroll
    for (int i = 0; i < 16; ++i) {
        int r = ty + i * 4;
        tile[r][tx] = src[(size_t)(r0 + r) * 1024 + q0 + tx];
    }
    __syncthreads();
#pragma unroll
    for (int i = 0; i < 16; ++i) {
        int q = ty + i * 4;
        dst[(size_t)(q0 + q) * 16384 + r0 + tx] = tile[tx][q];
    }
}

// ---------------- kernel 2: per-column top-32 (iterative extraction) ----------------
// one workgroup (256 thr) per (b, q). Each thread owns rows {tid, tid+256, ...} (64 values
// in registers). Winner extraction: wave shuffle-reduce -> 4 wave maxima -> thread 0.
// Tie-break: lower global index wins (matches jax.lax.top_k).
__global__ __launch_bounds__(256) void topk_kernel(const float* __restrict__ qk_T,
                                                   float* __restrict__ out_idx,
                                                   float* __restrict__ out_val,
                                                   int* __restrict__ idx_sorted) {
    int bid = blockIdx.x;              // b*1024 + q
    int tid = threadIdx.x;
    const float* row = qk_T + (size_t)bid * 16384;

    float v[64];
#pragma unroll
    for (int e = 0; e < 64; ++e) v[e] = row[e * 256 + tid];   // coalesced per e

    unsigned long long used = 0ull;
    float cv = v[0]; int ci = 0;       // ci = local slot e; global idx = e*256+tid
#pragma unroll
    for (int e = 1; e < 64; ++e) { if (v[e] > cv) { cv = v[e]; ci = e; } }

    __shared__ float wv[4]; __shared__ int wi[4];
    __shared__ float gv;   __shared__ int gi;
    __shared__ float sel_val[32]; __shared__ int sel_idx[32];

#pragma unroll 1
    for (int s = 0; s < 32; ++s) {
        float rv = cv; int ri = ci * 256 + tid;
#pragma unroll
        for (int off = 32; off >= 1; off >>= 1) {
            float ov = __shfl_xor(rv, off, 64);
            int   oi = __shfl_xor(ri, off, 64);
            if (ov > rv || (ov == rv && oi < ri)) { rv = ov; ri = oi; }
        }
        int w = tid >> 6;
        if ((tid & 63) == 0) { wv[w] = rv; wi[w] = ri; }
        __syncthreads();
        if (tid == 0) {
            float bv = wv[0]; int bi = wi[0];
#pragma unroll
            for (int k = 1; k < 4; ++k)
                if (wv[k] > bv || (wv[k] == bv && wi[k] < bi)) { bv = wv[k]; bi = wi[k]; }
            gv = bv; gi = bi;
            sel_val[s] = bv; sel_idx[s] = bi;
        }
        __syncthreads();
        int widx = gi;
        (void)gv;
        if ((widx & 255) == tid) {     // owner re-scans its 64 values
            used |= 1ull << (widx >> 8);
            cv = -__builtin_inff(); ci = 0;
#pragma unroll
            for (int e = 0; e < 64; ++e) {
                if (!((used >> e) & 1ull) && v[e] > cv) { cv = v[e]; ci = e; }
            }
        }
        // no barrier needed here: gi/wv next writes are after the next barrier
    }

    if (tid < 8) {
        out_val[(size_t)bid * 8 + tid] = sel_val[tid];
        out_idx[(size_t)bid * 8 + tid] = (float)sel_idx[tid];   // out buffer is f32
    }
    if (tid < 32) {                    // rank-sort the 32 (distinct) indices ascending
        int mine = sel_idx[tid];
        int rank = 0;
#pragma unroll
        for (int j = 0; j < 32; ++j) rank += (sel_idx[j] < mine) ? 1 : 0;
        idx_sorted[(size_t)bid * 32 + rank] = mine;
    }
}

// ---------------- kernel 3: blockify [B,D,T,64,64] -> [B, T*1024, 4, D] ----------------
// write-coalesced (thread per output element); reads get L2/L3 line reuse from
// neighboring blocks.
template <int D, int T>
__global__ __launch_bounds__(256) void blockify(const float* __restrict__ in,
                                                float* __restrict__ out) {
    int o = blockIdx.x * 256 + threadIdx.x;
    int c    = o & (D - 1);
    int rest = o / D;
    int p    = rest & 3; rest >>= 2;
    int n    = rest & (T * 1024 - 1);
    int b    = rest / (T * 1024);
    int wb = n & 31, hb = (n >> 5) & 31, t = n >> 10;
    int si = p >> 1, sj = p & 1;
    int y = hb * 2 + si, x = wb * 2 + sj;
    out[o] = in[((((size_t)b * D + c) * T + t) * 64 + y) * 64 + x];
}

// ---------------- kernel 4: gathered block attention ----------------
// one workgroup (256 thr) per (b, h_ref, w_ref). 4 queries x 128 keys x D_e=128 -> softmax
// -> x V (D_o=256). K staged in LDS in two 64-key halves (33KB, pad 129); wave w owns
// query w; PV streams m_out_b coalesced with thread-per-d.
__global__ __launch_bounds__(256) void attn_kernel(const float* __restrict__ m_in_b,
                                                   const float* __restrict__ m_out_b,
                                                   const float* __restrict__ q_b,
                                                   const int* __restrict__ idx_sorted,
                                                   float* __restrict__ out) {
    int bid = blockIdx.x;              // b*1024 + qblk
    int b = bid >> 10, qblk = bid & 1023;
    int hb = qblk >> 5, wb = qblk & 31;
    int tid = threadIdx.x;
    int w = tid >> 6, lane = tid & 63;

    __shared__ float K[64][129];       // one 64-key half, padded
    __shared__ float Q[4][128];
    __shared__ float P[4][128];
    __shared__ int   blks[32];

    if (tid < 32) blks[tid] = idx_sorted[(size_t)bid * 32 + tid];
    {
        const float* qsrc = q_b + (size_t)bid * 512;
        ((float*)Q)[tid]       = qsrc[tid];
        ((float*)Q)[tid + 256] = qsrc[tid + 256];
    }
    __syncthreads();

    const float scale = 0.08838834764831845f;  // 1/sqrt(128)
    float s01[2];
#pragma unroll 1
    for (int half = 0; half < 2; ++half) {
        if (half) __syncthreads();     // all reads of previous K half done
#pragma unroll 4
        for (int ki = 0; ki < 16; ++ki) {
            int blk = blks[half * 16 + ki];
            const float* src = m_in_b + ((size_t)b * 16384 + blk) * 512;
            int p0 = tid >> 7, c0 = tid & 127;
            K[ki * 4 + p0][c0]     = src[tid];
            K[ki * 4 + p0 + 2][c0] = src[tid + 256];
        }
        __syncthreads();
        float acc = 0.f;
#pragma unroll 4
        for (int c = 0; c < 128; ++c) acc += K[lane][c] * Q[w][c];
        s01[half] = acc * scale;
    }

    // softmax over 128 keys, per wave (query w). n = half*64 + lane.
    float m = fmaxf(s01[0], s01[1]);
#pragma unroll
    for (int off = 32; off >= 1; off >>= 1) m = fmaxf(m, __shfl_xor(m, off, 64));
    float e0 = expf(s01[0] - m), e1 = expf(s01[1] - m);
    float sum = e0 + e1;
#pragma unroll
    for (int off = 32; off >= 1; off >>= 1) sum += __shfl_xor(sum, off, 64);
    float inv = 1.0f / sum;
    P[w][lane]      = e0 * inv;
    P[w][lane + 64] = e1 * inv;
    __syncthreads();

    // PV: thread d = tid accumulates 4 outputs
    float a0 = 0.f, a1 = 0.f, a2 = 0.f, a3 = 0.f;
    int d = tid;
#pragma unroll 1
    for (int ki = 0; ki < 32; ++ki) {
        const float* vsrc = m_out_b + ((size_t)b * 16384 + blks[ki]) * 1024;
#pragma unroll
        for (int p = 0; p < 4; ++p) {
            float vv = vsrc[p * 256 + d];
            int n = ki * 4 + p;
            a0 += P[0][n] * vv; a1 += P[1][n] * vv;
            a2 += P[2][n] * vv; a3 += P[3][n] * vv;
        }
    }
    size_t base = (((size_t)b * 256 + d) * 64 + hb * 2) * 64 + wb * 2;
    out[base]      = a0;   // (i=0,j=0)
    out[base + 1]  = a1;   // (i=0,j=1)
    out[base + 64] = a2;   // (i=1,j=0)
    out[base + 65] = a3;   // (i=1,j=1)
}

extern "C" void kernel_launch(void* const* d_in, const int* in_sizes, int n_in,
                              void* d_out, int out_size, void* d_ws, size_t ws_size,
                              hipStream_t stream) {
    const float* m_in  = (const float*)d_in[0];   // [2,128,16,64,64]
    const float* m_out = (const float*)d_in[1];   // [2,256,16,64,64]
    const float* q_in  = (const float*)d_in[2];   // [2,128,64,64]
    const float* qk    = (const float*)d_in[3];   // [2,16384,1024]

    char* ws = (char*)d_ws;
    float* qk_T    = (float*)(ws);                 // 134,217,728 B
    float* m_out_b = (float*)(ws);                 // reuses qk_T region (stream-ordered)
    float* m_in_b  = (float*)(ws + 134217728);     // 67,108,864 B
    float* q_b     = (float*)(ws + 201326592);     // 4,194,304 B
    int*   idxs    = (int*)  (ws + 205520896);     // 262,144 B

    float* out     = (float*)d_out;
    float* out_mem = out;                          // [2,256,64,64] = 2,097,152
    float* out_idx = out + 2097152;                // [2,1024,8]    = 16,384
    float* out_val = out + 2113536;                // [2,1024,8]    = 16,384

    // 1. transpose qk_ref so top-k reads rows coalesced
    transpose_qk<<<dim3(256, 16, 2), 256, 0, stream>>>(qk, qk_T);
    // 2. top-32 per (b, q); writes idx/val outputs + sorted gather list
    topk_kernel<<<2048, 256, 0, stream>>>(qk_T, out_idx, out_val, idxs);
    // 3. blockify m_in and q_in (m_in_b needed by attention K-stage)
    blockify<128, 16><<<65536, 256, 0, stream>>>(m_in, m_in_b);
    blockify<128, 1><<<4096, 256, 0, stream>>>(q_in, q_b);
    // 4. blockify m_out into the (now dead) qk_T region
    blockify<256, 16><<<131072, 256, 0, stream>>>(m_out, m_out_b);
    // 5. gathered attention
    attn_kernel<<<2048, 256, 0, stream>>>(m_in_b, m_out_b, q_b, idxs, out_mem);
}

// Round 2
// 589.123 us; speedup vs baseline: 1.3536x; 1.3536x over previous
//
#include <hip/hip_runtime.h>
#include <math.h>

// Problem constants: B=2, D_e=128, D_o=256, T=16, H=W=64, H_ref=W_ref=32, s=2, k=32
// n_blocks = T*H_ref*W_ref = 16384 per batch; HW_ref = 1024 query blocks per batch.

// ---------------- workspace layout (bytes) ----------------
// [0, 134217728)      : qk_T [2][1024][16384] f32   (later reused as m_out_b [2][16384][4][256])
// [134217728, +64MB)  : m_in_b [2][16384][4][128] f32
// [201326592, +4MB)   : q_b [2][1024][4][128] f32
// [205520896, +256KB) : idx_sorted [2][1024][32] int32

// ---------------- kernel 1: transpose qk_ref [B,16384,1024] -> [B,1024,16384] ----------------
__global__ __launch_bounds__(256) void transpose_qk(const float* __restrict__ in,
                                                    float* __restrict__ out) {
    __shared__ float tile[64][65];
    int r0 = blockIdx.x * 64;          // row tile (16384 dim)
    int q0 = blockIdx.y * 64;          // col tile (1024 dim)
    int b  = blockIdx.z;
    const float* src = in  + (size_t)b * 16384 * 1024;
    float*       dst = out + (size_t)b * 1024 * 16384;
    int tx = threadIdx.x & 63;
    int ty = threadIdx.x >> 6;         // 0..3
#pragma unroll
    for (int i = 0; i < 16; ++i) {
        int r = ty + i * 4;
        tile[r][tx] = src[(size_t)(r0 + r) * 1024 + q0 + tx];
    }
    __syncthreads();
#pragma unroll
    for (int i = 0; i < 16; ++i) {
        int q = ty + i * 4;
        dst[(size_t)(q0 + q) * 16384 + r0 + tx] = tile[tx][q];
    }
}

// ---------------- kernel 2: per-column top-32 (iterative extraction) ----------------
__global__ __launch_bounds__(256) void topk_kernel(const float* __restrict__ qk_T,
                                                   float* __restrict__ out_idx,
                                                   float* __restrict__ out_val,
                                                   int* __restrict__ idx_sorted) {
    int bid = blockIdx.x;              // b*1024 + q
    int tid = threadIdx.x;
    const float* row = qk_T + (size_t)bid * 16384;

    float v[64];
#pragma unroll
    for (int e = 0; e < 64; ++e) v[e] = row[e * 256 + tid];   // coalesced per e

    unsigned long long used = 0ull;
    float cv = v[0]; int ci = 0;       // ci = local slot e; global idx = e*256+tid
#pragma unroll
    for (int e = 1; e < 64; ++e) { if (v[e] > cv) { cv = v[e]; ci = e; } }

    __shared__ float wv[4]; __shared__ int wi[4];
    __shared__ float gv;   __shared__ int gi;
    __shared__ float sel_val[32]; __shared__ int sel_idx[32];

#pragma unroll 1
    for (int s = 0; s < 32; ++s) {
        float rv = cv; int ri = ci * 256 + tid;
#pragma unroll
        for (int off = 32; off >= 1; off >>= 1) {
            float ov = __shfl_xor(rv, off, 64);
            int   oi = __shfl_xor(ri, off, 64);
            if (ov > rv || (ov == rv && oi < ri)) { rv = ov; ri = oi; }
        }
        int w = tid >> 6;
        if ((tid & 63) == 0) { wv[w] = rv; wi[w] = ri; }
        __syncthreads();
        if (tid == 0) {
            float bv = wv[0]; int bi = wi[0];
#pragma unroll
            for (int k = 1; k < 4; ++k)
                if (wv[k] > bv || (wv[k] == bv && wi[k] < bi)) { bv = wv[k]; bi = wi[k]; }
            gv = bv; gi = bi;
            sel_val[s] = bv; sel_idx[s] = bi;
        }
        __syncthreads();
        int widx = gi;
        (void)gv;
        if ((widx & 255) == tid) {     // owner re-scans its 64 values
            used |= 1ull << (widx >> 8);
            cv = -__builtin_inff(); ci = 0;
#pragma unroll
            for (int e = 0; e < 64; ++e) {
                if (!((used >> e) & 1ull) && v[e] > cv) { cv = v[e]; ci = e; }
            }
        }
    }

    if (tid < 8) {
        out_val[(size_t)bid * 8 + tid] = sel_val[tid];
        out_idx[(size_t)bid * 8 + tid] = (float)sel_idx[tid];   // out buffer is f32
    }
    if (tid < 32) {                    // rank-sort the 32 (distinct) indices ascending
        int mine = sel_idx[tid];
        int rank = 0;
#pragma unroll
        for (int j = 0; j < 32; ++j) rank += (sel_idx[j] < mine) ? 1 : 0;
        idx_sorted[(size_t)bid * 32 + rank] = mine;
    }
}

// ---------------- kernel 3: LDS-tiled blockify [B,D,T,64,64] -> [B, T*1024, 4, D] ----------------
// workgroup = (b, t, hb, 64-channel chunk). Reads: 256B contiguous rows (c,si) x 64x.
// Writes: 256B contiguous (wb,p) segments of 64 channels. LDS tile padded to 129 floats
// inner stride -> bank-stride 1 on the strided read side (conflict-free).
template <int D, int T>
__global__ __launch_bounds__(256) void blockify_tiled(const float* __restrict__ in,
                                                      float* __restrict__ out) {
    constexpr int NCH = D / 64;
    int wg = blockIdx.x;
    int ch = wg % NCH;
    int hb = (wg / NCH) % 32;
    int t  = (wg / (NCH * 32)) % T;
    int b  = wg / (NCH * 32 * T);
    int c0 = ch * 64;
    int tid = threadIdx.x;

    __shared__ float tile[64][129];    // [c][si*64+x], padded

    // read stage: 128 rows (c,si), 4 rows/iter (one per wave), 32 iters
    {
        int x = tid & 63;
        int rw = tid >> 6;             // 0..3
#pragma unroll 8
        for (int i = 0; i < 32; ++i) {
            int r = i * 4 + rw;        // 0..127
            int c = r >> 1, si = r & 1;
            tile[c][si * 64 + x] =
                in[((((size_t)b * D + c0 + c) * T + t) * 64 + (2 * hb + si)) * 64 + x];
        }
    }
    __syncthreads();

    // write stage: iterate wb; wave p writes 64 consecutive channels
    {
        int p = tid >> 6;              // 0..3
        int cc = tid & 63;
        int si = p >> 1, sj = p & 1;
        size_t nbase = (((size_t)b * T + t) * 1024 + (size_t)hb * 32);
#pragma unroll 8
        for (int wb = 0; wb < 32; ++wb) {
            out[(nbase + wb) * 4 * D + (size_t)p * D + c0 + cc] =
                tile[cc][si * 64 + 2 * wb + sj];
        }
    }
}

// ---------------- kernel 4: gathered block attention ----------------
__global__ __launch_bounds__(256) void attn_kernel(const float* __restrict__ m_in_b,
                                                   const float* __restrict__ m_out_b,
                                                   const float* __restrict__ q_b,
                                                   const int* __restrict__ idx_sorted,
                                                   float* __restrict__ out) {
    int bid = blockIdx.x;              // b*1024 + qblk
    int b = bid >> 10, qblk = bid & 1023;
    int hb = qblk >> 5, wb = qblk & 31;
    int tid = threadIdx.x;
    int w = tid >> 6, lane = tid & 63;

    __shared__ float K[64][129];       // one 64-key half, padded
    __shared__ float Q[4][128];
    __shared__ float P[4][128];
    __shared__ int   blks[32];

    if (tid < 32) blks[tid] = idx_sorted[(size_t)bid * 32 + tid];
    {
        const float* qsrc = q_b + (size_t)bid * 512;
        ((float*)Q)[tid]       = qsrc[tid];
        ((float*)Q)[tid + 256] = qsrc[tid + 256];
    }
    __syncthreads();

    const float scale = 0.08838834764831845f;  // 1/sqrt(128)
    float s01[2];
#pragma unroll 1
    for (int half = 0; half < 2; ++half) {
        if (half) __syncthreads();
#pragma unroll 4
        for (int ki = 0; ki < 16; ++ki) {
            int blk = blks[half * 16 + ki];
            const float* src = m_in_b + ((size_t)b * 16384 + blk) * 512;
            int p0 = tid >> 7, c0 = tid & 127;
            K[ki * 4 + p0][c0]     = src[tid];
            K[ki * 4 + p0 + 2][c0] = src[tid + 256];
        }
        __syncthreads();
        float acc = 0.f;
#pragma unroll 4
        for (int c = 0; c < 128; ++c) acc += K[lane][c] * Q[w][c];
        s01[half] = acc * scale;
    }

    float m = fmaxf(s01[0], s01[1]);
#pragma unroll
    for (int off = 32; off >= 1; off >>= 1) m = fmaxf(m, __shfl_xor(m, off, 64));
    float e0 = expf(s01[0] - m), e1 = expf(s01[1] - m);
    float sum = e0 + e1;
#pragma unroll
    for (int off = 32; off >= 1; off >>= 1) sum += __shfl_xor(sum, off, 64);
    float inv = 1.0f / sum;
    P[w][lane]      = e0 * inv;
    P[w][lane + 64] = e1 * inv;
    __syncthreads();

    float a0 = 0.f, a1 = 0.f, a2 = 0.f, a3 = 0.f;
    int d = tid;
#pragma unroll 1
    for (int ki = 0; ki < 32; ++ki) {
        const float* vsrc = m_out_b + ((size_t)b * 16384 + blks[ki]) * 1024;
#pragma unroll
        for (int p = 0; p < 4; ++p) {
            float vv = vsrc[p * 256 + d];
            int n = ki * 4 + p;
            a0 += P[0][n] * vv; a1 += P[1][n] * vv;
            a2 += P[2][n] * vv; a3 += P[3][n] * vv;
        }
    }
    size_t base = (((size_t)b * 256 + d) * 64 + hb * 2) * 64 + wb * 2;
    out[base]      = a0;
    out[base + 1]  = a1;
    out[base + 64] = a2;
    out[base + 65] = a3;
}

extern "C" void kernel_launch(void* const* d_in, const int* in_sizes, int n_in,
                              void* d_out, int out_size, void* d_ws, size_t ws_size,
                              hipStream_t stream) {
    const float* m_in  = (const float*)d_in[0];   // [2,128,16,64,64]
    const float* m_out = (const float*)d_in[1];   // [2,256,16,64,64]
    const float* q_in  = (const float*)d_in[2];   // [2,128,64,64]
    const float* qk    = (const float*)d_in[3];   // [2,16384,1024]

    char* ws = (char*)d_ws;
    float* qk_T    = (float*)(ws);                 // 134,217,728 B
    float* m_out_b = (float*)(ws);                 // reuses qk_T region (stream-ordered)
    float* m_in_b  = (float*)(ws + 134217728);     // 67,108,864 B
    float* q_b     = (float*)(ws + 201326592);     // 4,194,304 B
    int*   idxs    = (int*)  (ws + 205520896);     // 262,144 B

    float* out     = (float*)d_out;
    float* out_mem = out;                          // [2,256,64,64]
    float* out_idx = out + 2097152;                // [2,1024,8]
    float* out_val = out + 2113536;                // [2,1024,8]

    transpose_qk<<<dim3(256, 16, 2), 256, 0, stream>>>(qk, qk_T);
    topk_kernel<<<2048, 256, 0, stream>>>(qk_T, out_idx, out_val, idxs);
    blockify_tiled<128, 16><<<2 * 16 * 32 * 2, 256, 0, stream>>>(m_in, m_in_b);
    blockify_tiled<128, 1><<<2 * 1 * 32 * 2, 256, 0, stream>>>(q_in, q_b);
    blockify_tiled<256, 16><<<2 * 16 * 32 * 4, 256, 0, stream>>>(m_out, m_out_b);
    attn_kernel<<<2048, 256, 0, stream>>>(m_in_b, m_out_b, q_b, idxs, out_mem);
}

// Round 3
// 587.652 us; speedup vs baseline: 1.3569x; 1.0025x over previous
//
#include <hip/hip_runtime.h>
#include <math.h>

// Problem constants: B=2, D_e=128, D_o=256, T=16, H=W=64, H_ref=W_ref=32, s=2, k=32
// n_blocks = T*H_ref*W_ref = 16384 per batch; HW_ref = 1024 query blocks per batch.

// ---------------- workspace layout (bytes) ----------------
// [0, 134217728)      : qk_T [2][1024][16384] f32   (later reused as m_out_b [2][16384][4][256])
// [134217728, +64MB)  : m_in_b [2][16384][4][128] f32
// [201326592, +4MB)   : q_b [2][1024][4][128] f32
// [205520896, +256KB) : idx_sorted [2][1024][32] int32

// ---------------- kernel 1: transpose qk_ref [B,16384,1024] -> [B,1024,16384] ----------------
__global__ __launch_bounds__(256) void transpose_qk(const float* __restrict__ in,
                                                    float* __restrict__ out) {
    __shared__ float tile[64][65];
    int r0 = blockIdx.x * 64;          // row tile (16384 dim)
    int q0 = blockIdx.y * 64;          // col tile (1024 dim)
    int b  = blockIdx.z;
    const float* src = in  + (size_t)b * 16384 * 1024;
    float*       dst = out + (size_t)b * 1024 * 16384;
    int tx = threadIdx.x & 63;
    int ty = threadIdx.x >> 6;         // 0..3
#pragma unroll
    for (int i = 0; i < 16; ++i) {
        int r = ty + i * 4;
        tile[r][tx] = src[(size_t)(r0 + r) * 1024 + q0 + tx];
    }
    __syncthreads();
#pragma unroll
    for (int i = 0; i < 16; ++i) {
        int q = ty + i * 4;
        dst[(size_t)(q0 + q) * 16384 + r0 + tx] = tile[tx][q];
    }
}

// ---------------- kernel 2: per-column top-32, register-resident ----------------
// 512 threads/wg, one wg per (b,q). Each thread owns 32 values (VGPR-resident, no
// reload). 32 extraction rounds, ONE barrier per round via double-buffered
// cross-wave candidate slots. Tie-break: lower global index (matches jax top_k).
__global__ __launch_bounds__(512) void topk_kernel(const float* __restrict__ qk_T,
                                                   float* __restrict__ out_idx,
                                                   float* __restrict__ out_val,
                                                   int* __restrict__ idx_sorted) {
    int bid = blockIdx.x;              // b*1024 + q
    int tid = threadIdx.x;
    const float* row = qk_T + (size_t)bid * 16384;

    float v[32];
#pragma unroll
    for (int e = 0; e < 32; ++e) v[e] = row[e * 512 + tid];   // coalesced per e

    unsigned used = 0u;
    float cv = v[0]; int ci = 0;       // global idx = e*512 + tid
#pragma unroll
    for (int e = 1; e < 32; ++e) { if (v[e] > cv) { cv = v[e]; ci = e; } }

    __shared__ float wv[2][8];
    __shared__ int   wi[2][8];
    __shared__ float sel_val[32];
    __shared__ int   sel_idx[32];

    int w = tid >> 6, lane = tid & 63;

#pragma unroll 1
    for (int s = 0; s < 32; ++s) {
        // wave-level argmax (lowest index wins ties)
        float rv = cv; int ri = ci * 512 + tid;
#pragma unroll
        for (int off = 32; off >= 1; off >>= 1) {
            float ov = __shfl_xor(rv, off, 64);
            int   oi = __shfl_xor(ri, off, 64);
            if (ov > rv || (ov == rv && oi < ri)) { rv = ov; ri = oi; }
        }
        int buf = s & 1;
        if (lane == 0) { wv[buf][w] = rv; wi[buf][w] = ri; }
        __syncthreads();
        // every thread scans the 8 wave winners (LDS broadcast reads)
        float bv = wv[buf][0]; int bi = wi[buf][0];
#pragma unroll
        for (int j = 1; j < 8; ++j) {
            float jv = wv[buf][j]; int ji = wi[buf][j];
            if (jv > bv || (jv == bv && ji < bi)) { bv = jv; bi = ji; }
        }
        if (tid == 0) { sel_val[s] = bv; sel_idx[s] = bi; }
        // owner pops its winner and rescans its 32 register values
        if ((bi & 511) == tid) {
            used |= 1u << (bi >> 9);
            cv = -__builtin_inff(); ci = 0;
#pragma unroll
            for (int e = 0; e < 32; ++e) {
                if (!((used >> e) & 1u) && v[e] > cv) { cv = v[e]; ci = e; }
            }
        }
        // no second barrier: next round writes the other buffer; the round-(s+1)
        // barrier fences the round-(s+2) overwrite of this buffer.
    }
    __syncthreads();

    if (tid < 8) {
        out_val[(size_t)bid * 8 + tid] = sel_val[tid];
        out_idx[(size_t)bid * 8 + tid] = (float)sel_idx[tid];   // out buffer is f32
    }
    if (tid < 32) {                    // rank-sort the 32 (distinct) indices ascending
        int mine = sel_idx[tid];
        int rank = 0;
#pragma unroll
        for (int j = 0; j < 32; ++j) rank += (sel_idx[j] < mine) ? 1 : 0;
        idx_sorted[(size_t)bid * 32 + rank] = mine;
    }
}

// ---------------- kernel 3: LDS-tiled blockify [B,D,T,64,64] -> [B, T*1024, 4, D] ----------------
// workgroup = (b, t, hb, 64-channel chunk). Reads: 256B contiguous rows (c,si) x 64x.
// Writes: 256B contiguous (wb,p) segments of 64 channels. LDS tile padded to 129 floats
// inner stride -> bank-stride 1 on the strided read side (conflict-free).
template <int D, int T>
__global__ __launch_bounds__(256) void blockify_tiled(const float* __restrict__ in,
                                                      float* __restrict__ out) {
    constexpr int NCH = D / 64;
    int wg = blockIdx.x;
    int ch = wg % NCH;
    int hb = (wg / NCH) % 32;
    int t  = (wg / (NCH * 32)) % T;
    int b  = wg / (NCH * 32 * T);
    int c0 = ch * 64;
    int tid = threadIdx.x;

    __shared__ float tile[64][129];    // [c][si*64+x], padded

    {
        int x = tid & 63;
        int rw = tid >> 6;             // 0..3
#pragma unroll 8
        for (int i = 0; i < 32; ++i) {
            int r = i * 4 + rw;        // 0..127
            int c = r >> 1, si = r & 1;
            tile[c][si * 64 + x] =
                in[((((size_t)b * D + c0 + c) * T + t) * 64 + (2 * hb + si)) * 64 + x];
        }
    }
    __syncthreads();

    {
        int p = tid >> 6;              // 0..3
        int cc = tid & 63;
        int si = p >> 1, sj = p & 1;
        size_t nbase = (((size_t)b * T + t) * 1024 + (size_t)hb * 32);
#pragma unroll 8
        for (int wb = 0; wb < 32; ++wb) {
            out[(nbase + wb) * 4 * D + (size_t)p * D + c0 + cc] =
                tile[cc][si * 64 + 2 * wb + sj];
        }
    }
}

// ---------------- kernel 4: gathered block attention ----------------
__global__ __launch_bounds__(256) void attn_kernel(const float* __restrict__ m_in_b,
                                                   const float* __restrict__ m_out_b,
                                                   const float* __restrict__ q_b,
                                                   const int* __restrict__ idx_sorted,
                                                   float* __restrict__ out) {
    int bid = blockIdx.x;              // b*1024 + qblk
    int b = bid >> 10, qblk = bid & 1023;
    int hb = qblk >> 5, wb = qblk & 31;
    int tid = threadIdx.x;
    int w = tid >> 6, lane = tid & 63;

    __shared__ float K[64][129];       // one 64-key half, padded
    __shared__ float Q[4][128];
    __shared__ float P[4][128];
    __shared__ int   blks[32];

    if (tid < 32) blks[tid] = idx_sorted[(size_t)bid * 32 + tid];
    {
        const float* qsrc = q_b + (size_t)bid * 512;
        ((float*)Q)[tid]       = qsrc[tid];
        ((float*)Q)[tid + 256] = qsrc[tid + 256];
    }
    __syncthreads();

    const float scale = 0.08838834764831845f;  // 1/sqrt(128)
    float s01[2];
#pragma unroll 1
    for (int half = 0; half < 2; ++half) {
        if (half) __syncthreads();
#pragma unroll 4
        for (int ki = 0; ki < 16; ++ki) {
            int blk = blks[half * 16 + ki];
            const float* src = m_in_b + ((size_t)b * 16384 + blk) * 512;
            int p0 = tid >> 7, c0 = tid & 127;
            K[ki * 4 + p0][c0]     = src[tid];
            K[ki * 4 + p0 + 2][c0] = src[tid + 256];
        }
        __syncthreads();
        float acc = 0.f;
#pragma unroll 4
        for (int c = 0; c < 128; ++c) acc += K[lane][c] * Q[w][c];
        s01[half] = acc * scale;
    }

    float m = fmaxf(s01[0], s01[1]);
#pragma unroll
    for (int off = 32; off >= 1; off >>= 1) m = fmaxf(m, __shfl_xor(m, off, 64));
    float e0 = expf(s01[0] - m), e1 = expf(s01[1] - m);
    float sum = e0 + e1;
#pragma unroll
    for (int off = 32; off >= 1; off >>= 1) sum += __shfl_xor(sum, off, 64);
    float inv = 1.0f / sum;
    P[w][lane]      = e0 * inv;
    P[w][lane + 64] = e1 * inv;
    __syncthreads();

    float a0 = 0.f, a1 = 0.f, a2 = 0.f, a3 = 0.f;
    int d = tid;
#pragma unroll 1
    for (int ki = 0; ki < 32; ++ki) {
        const float* vsrc = m_out_b + ((size_t)b * 16384 + blks[ki]) * 1024;
#pragma unroll
        for (int p = 0; p < 4; ++p) {
            float vv = vsrc[p * 256 + d];
            int n = ki * 4 + p;
            a0 += P[0][n] * vv; a1 += P[1][n] * vv;
            a2 += P[2][n] * vv; a3 += P[3][n] * vv;
        }
    }
    size_t base = (((size_t)b * 256 + d) * 64 + hb * 2) * 64 + wb * 2;
    out[base]      = a0;
    out[base + 1]  = a1;
    out[base + 64] = a2;
    out[base + 65] = a3;
}

extern "C" void kernel_launch(void* const* d_in, const int* in_sizes, int n_in,
                              void* d_out, int out_size, void* d_ws, size_t ws_size,
                              hipStream_t stream) {
    const float* m_in  = (const float*)d_in[0];   // [2,128,16,64,64]
    const float* m_out = (const float*)d_in[1];   // [2,256,16,64,64]
    const float* q_in  = (const float*)d_in[2];   // [2,128,64,64]
    const float* qk    = (const float*)d_in[3];   // [2,16384,1024]

    char* ws = (char*)d_ws;
    float* qk_T    = (float*)(ws);                 // 134,217,728 B
    float* m_out_b = (float*)(ws);                 // reuses qk_T region (stream-ordered)
    float* m_in_b  = (float*)(ws + 134217728);     // 67,108,864 B
    float* q_b     = (float*)(ws + 201326592);     // 4,194,304 B
    int*   idxs    = (int*)  (ws + 205520896);     // 262,144 B

    float* out     = (float*)d_out;
    float* out_mem = out;                          // [2,256,64,64]
    float* out_idx = out + 2097152;                // [2,1024,8]
    float* out_val = out + 2113536;                // [2,1024,8]

    transpose_qk<<<dim3(256, 16, 2), 256, 0, stream>>>(qk, qk_T);
    topk_kernel<<<2048, 512, 0, stream>>>(qk_T, out_idx, out_val, idxs);
    blockify_tiled<128, 16><<<2 * 16 * 32 * 2, 256, 0, stream>>>(m_in, m_in_b);
    blockify_tiled<128, 1><<<2 * 1 * 32 * 2, 256, 0, stream>>>(q_in, q_b);
    blockify_tiled<256, 16><<<2 * 16 * 32 * 4, 256, 0, stream>>>(m_out, m_out_b);
    attn_kernel<<<2048, 256, 0, stream>>>(m_in_b, m_out_b, q_b, idxs, out_mem);
}

// Round 4
// 467.538 us; speedup vs baseline: 1.7055x; 1.2569x over previous
//
#include <hip/hip_runtime.h>
#include <math.h>

// Problem constants: B=2, D_e=128, D_o=256, T=16, H=W=64, H_ref=W_ref=32, s=2, k=32
// n_blocks = T*H_ref*W_ref = 16384 per batch; HW_ref = 1024 query blocks per batch.

// ---------------- workspace layout (bytes) ----------------
// [0, 134217728)      : qk_T [2][1024][16384] f32   (later reused as m_out_b [2][16384][4][256])
// [134217728, +64MB)  : m_in_b [2][16384][4][128] f32
// [201326592, +4MB)   : q_b [2][1024][4][128] f32
// [205520896, +256KB) : idx_sorted [2][1024][32] int32

// ---------------- kernel 1: transpose qk_ref [B,16384,1024] -> [B,1024,16384] ----------------
__global__ __launch_bounds__(256) void transpose_qk(const float* __restrict__ in,
                                                    float* __restrict__ out) {
    __shared__ float tile[64][65];
    int r0 = blockIdx.x * 64;
    int q0 = blockIdx.y * 64;
    int b  = blockIdx.z;
    const float* src = in  + (size_t)b * 16384 * 1024;
    float*       dst = out + (size_t)b * 1024 * 16384;
    int tx = threadIdx.x & 63;
    int ty = threadIdx.x >> 6;
#pragma unroll
    for (int i = 0; i < 16; ++i) {
        int r = ty + i * 4;
        tile[r][tx] = src[(size_t)(r0 + r) * 1024 + q0 + tx];
    }
    __syncthreads();
#pragma unroll
    for (int i = 0; i < 16; ++i) {
        int q = ty + i * 4;
        dst[(size_t)(q0 + q) * 16384 + r0 + tx] = tile[tx][q];
    }
}

// ---------------- kernel 2: top-32 via threshold filter + rank select ----------------
// 512 thr/wg, one wg per (b,q). Thread owns 32 reg-resident values (float4 loads).
// Monotonic u32 transform; 2-pass histogram of the 512 THREAD-MAXIMA gives a provably
// conservative threshold t (<= 32nd-largest global). Filter to ~45 candidates, exact
// top-32 by rank counting on packed (uval, 16383-idx) u64 keys (jax tie order).
__device__ inline unsigned mono_u32(float f) {
    unsigned b = __float_as_uint(f);
    return (b & 0x80000000u) ? ~b : (b | 0x80000000u);
}

__global__ __launch_bounds__(512) void topk_kernel(const float* __restrict__ qk_T,
                                                   float* __restrict__ out_idx,
                                                   float* __restrict__ out_val,
                                                   int* __restrict__ idx_sorted) {
    int bid = blockIdx.x;              // b*1024 + q
    int tid = threadIdx.x;
    const float4* row4 = (const float4*)(qk_T + (size_t)bid * 16384);

    float v[32];
#pragma unroll
    for (int g = 0; g < 8; ++g) {
        float4 t4 = row4[g * 512 + tid];      // float idx g*2048 + tid*4
        v[g * 4 + 0] = t4.x; v[g * 4 + 1] = t4.y;
        v[g * 4 + 2] = t4.z; v[g * 4 + 3] = t4.w;
    }
    // gi(e) = (e>>2)*2048 + tid*4 + (e&3)  — monotone in e for fixed thread

    float cv = v[0]; int ci = 0;       // thread max (lowest e on tie -> lowest gi)
#pragma unroll
    for (int e = 1; e < 32; ++e) { if (v[e] > cv) { cv = v[e]; ci = e; } }

    __shared__ int hist1[256];
    __shared__ int hist2[256];
    __shared__ int s_b1, s_above1, s_cnt;
    __shared__ unsigned s_tu;
    __shared__ unsigned long long cand[512];
    __shared__ unsigned long long selk[32];
    __shared__ float wvf[2][8];
    __shared__ int   wif[2][8];

    if (tid < 256) { hist1[tid] = 0; hist2[tid] = 0; }
    if (tid == 0) s_cnt = 0;
    __syncthreads();

    unsigned um = mono_u32(cv);
    atomicAdd(&hist1[um >> 24], 1);
    __syncthreads();

    // pass 1: find byte b1 containing rank-32 of maxima (from top), count strictly above
    if (tid < 64) {
        int base = 252 - 4 * tid;      // lane 0 covers top bins 252..255
        int h0 = hist1[base], h1 = hist1[base + 1], h2 = hist1[base + 2], h3 = hist1[base + 3];
        int gs = h0 + h1 + h2 + h3;
        int pre = gs;
#pragma unroll
        for (int off = 1; off < 64; off <<= 1) {
            int o = __shfl_up(pre, off, 64);
            if (tid >= off) pre += o;
        }
        int excl = pre - gs;           // maxima in higher groups
        if (excl < 32 && pre >= 32) {  // crossing group (exactly one lane)
            int c = excl, b, ab;
            c += h3; if (c >= 32) { b = base + 3; ab = c - h3; }
            else { c += h2; if (c >= 32) { b = base + 2; ab = c - h2; }
            else { c += h1; if (c >= 32) { b = base + 1; ab = c - h1; }
            else { c += h0;   b = base;     ab = c - h0; } } }
            s_b1 = b; s_above1 = ab;
        }
    }
    __syncthreads();
    int b1 = s_b1;
    if ((int)(um >> 24) == b1) atomicAdd(&hist2[(um >> 16) & 0xFF], 1);
    __syncthreads();

    // pass 2: refine to 16-bit prefix floor
    if (tid < 64) {
        int A = s_above1;
        int base = 252 - 4 * tid;
        int h0 = hist2[base], h1 = hist2[base + 1], h2 = hist2[base + 2], h3 = hist2[base + 3];
        int gs = h0 + h1 + h2 + h3;
        int pre = gs;
#pragma unroll
        for (int off = 1; off < 64; off <<= 1) {
            int o = __shfl_up(pre, off, 64);
            if (tid >= off) pre += o;
        }
        int excl = pre - gs;
        if (A + excl < 32 && A + pre >= 32) {
            int c = A + excl, b;
            c += h3; if (c >= 32) b = base + 3;
            else { c += h2; if (c >= 32) b = base + 2;
            else { c += h1; if (c >= 32) b = base + 1;
            else { b = base; } } }
            s_tu = (((unsigned)b1 << 8) | (unsigned)b) << 16;
        }
    }
    __syncthreads();
    unsigned tu = s_tu;

    // filter: keep values with u >= tu (superset of global top-32)
#pragma unroll
    for (int e = 0; e < 32; ++e) {
        unsigned ue = mono_u32(v[e]);
        if (ue >= tu) {
            int pos = atomicAdd(&s_cnt, 1);
            if (pos < 512) {
                int gi = (e >> 2) * 2048 + tid * 4 + (e & 3);
                cand[pos] = ((unsigned long long)ue << 32) |
                            (unsigned long long)(16383 - gi);
            }
        }
    }
    __syncthreads();
    int C = s_cnt;

    if (C <= 512) {
        if (tid < C) {
            unsigned long long mine = cand[tid];
            int rank = 0;
            for (int j = 0; j < C; ++j) rank += (cand[j] > mine) ? 1 : 0;
            if (rank < 32) selk[rank] = mine;
        }
        __syncthreads();
    } else {
        // fallback (pathological duplicates only): iterative extraction, exact
        unsigned used = 0u;
        int w = tid >> 6, lane = tid & 63;
#pragma unroll 1
        for (int s = 0; s < 32; ++s) {
            float rv = cv; int ri = (ci >> 2) * 2048 + tid * 4 + (ci & 3);
#pragma unroll
            for (int off = 32; off >= 1; off >>= 1) {
                float ov = __shfl_xor(rv, off, 64);
                int   oi = __shfl_xor(ri, off, 64);
                if (ov > rv || (ov == rv && oi < ri)) { rv = ov; ri = oi; }
            }
            int buf = s & 1;
            if (lane == 0) { wvf[buf][w] = rv; wif[buf][w] = ri; }
            __syncthreads();
            float bv = wvf[buf][0]; int bi = wif[buf][0];
#pragma unroll
            for (int j = 1; j < 8; ++j) {
                float jv = wvf[buf][j]; int ji = wif[buf][j];
                if (jv > bv || (jv == bv && ji < bi)) { bv = jv; bi = ji; }
            }
            if (tid == 0)
                selk[s] = ((unsigned long long)mono_u32(bv) << 32) |
                          (unsigned long long)(16383 - bi);
            if (((bi >> 2) & 511) == tid) {
                int be = ((bi >> 11) << 2) | (bi & 3);
                used |= 1u << be;
                cv = -__builtin_inff(); ci = 0;
#pragma unroll
                for (int e = 0; e < 32; ++e)
                    if (!((used >> e) & 1u) && v[e] > cv) { cv = v[e]; ci = e; }
            }
        }
        __syncthreads();
    }

    if (tid < 8) {
        unsigned long long k = selk[tid];
        unsigned uv = (unsigned)(k >> 32);
        unsigned bits = (uv & 0x80000000u) ? (uv ^ 0x80000000u) : ~uv;
        out_val[(size_t)bid * 8 + tid] = __uint_as_float(bits);
        int gi = 16383 - (int)(k & 0xFFFFFFFFull);
        out_idx[(size_t)bid * 8 + tid] = (float)gi;
    }
    if (tid < 32) {                    // 32 distinct indices -> ascending sort by rank
        int mine = 16383 - (int)(selk[tid] & 0xFFFFFFFFull);
        int rank = 0;
#pragma unroll
        for (int j = 0; j < 32; ++j) {
            int oj = 16383 - (int)(selk[j] & 0xFFFFFFFFull);
            rank += (oj < mine) ? 1 : 0;
        }
        idx_sorted[(size_t)bid * 32 + rank] = mine;
    }
}

// ---------------- kernel 3: LDS-tiled blockify [B,D,T,64,64] -> [B, T*1024, 4, D] ----------------
template <int D, int T>
__global__ __launch_bounds__(256) void blockify_tiled(const float* __restrict__ in,
                                                      float* __restrict__ out) {
    constexpr int NCH = D / 64;
    int wg = blockIdx.x;
    int ch = wg % NCH;
    int hb = (wg / NCH) % 32;
    int t  = (wg / (NCH * 32)) % T;
    int b  = wg / (NCH * 32 * T);
    int c0 = ch * 64;
    int tid = threadIdx.x;

    __shared__ float tile[64][129];

    {
        int x = tid & 63;
        int rw = tid >> 6;
#pragma unroll 8
        for (int i = 0; i < 32; ++i) {
            int r = i * 4 + rw;
            int c = r >> 1, si = r & 1;
            tile[c][si * 64 + x] =
                in[((((size_t)b * D + c0 + c) * T + t) * 64 + (2 * hb + si)) * 64 + x];
        }
    }
    __syncthreads();

    {
        int p = tid >> 6;
        int cc = tid & 63;
        int si = p >> 1, sj = p & 1;
        size_t nbase = (((size_t)b * T + t) * 1024 + (size_t)hb * 32);
#pragma unroll 8
        for (int wb = 0; wb < 32; ++wb) {
            out[(nbase + wb) * 4 * D + (size_t)p * D + c0 + cc] =
                tile[cc][si * 64 + 2 * wb + sj];
        }
    }
}

// ---------------- kernel 4: gathered block attention ----------------
__global__ __launch_bounds__(256) void attn_kernel(const float* __restrict__ m_in_b,
                                                   const float* __restrict__ m_out_b,
                                                   const float* __restrict__ q_b,
                                                   const int* __restrict__ idx_sorted,
                                                   float* __restrict__ out) {
    int bid = blockIdx.x;
    int b = bid >> 10, qblk = bid & 1023;
    int hb = qblk >> 5, wb = qblk & 31;
    int tid = threadIdx.x;
    int w = tid >> 6, lane = tid & 63;

    __shared__ float K[64][129];
    __shared__ float Q[4][128];
    __shared__ float P[4][128];
    __shared__ int   blks[32];

    if (tid < 32) blks[tid] = idx_sorted[(size_t)bid * 32 + tid];
    {
        const float* qsrc = q_b + (size_t)bid * 512;
        ((float*)Q)[tid]       = qsrc[tid];
        ((float*)Q)[tid + 256] = qsrc[tid + 256];
    }
    __syncthreads();

    const float scale = 0.08838834764831845f;
    float s01[2];
#pragma unroll 1
    for (int half = 0; half < 2; ++half) {
        if (half) __syncthreads();
#pragma unroll 4
        for (int ki = 0; ki < 16; ++ki) {
            int blk = blks[half * 16 + ki];
            const float* src = m_in_b + ((size_t)b * 16384 + blk) * 512;
            int p0 = tid >> 7, c0 = tid & 127;
            K[ki * 4 + p0][c0]     = src[tid];
            K[ki * 4 + p0 + 2][c0] = src[tid + 256];
        }
        __syncthreads();
        float acc = 0.f;
#pragma unroll 4
        for (int c = 0; c < 128; ++c) acc += K[lane][c] * Q[w][c];
        s01[half] = acc * scale;
    }

    float m = fmaxf(s01[0], s01[1]);
#pragma unroll
    for (int off = 32; off >= 1; off >>= 1) m = fmaxf(m, __shfl_xor(m, off, 64));
    float e0 = expf(s01[0] - m), e1 = expf(s01[1] - m);
    float sum = e0 + e1;
#pragma unroll
    for (int off = 32; off >= 1; off >>= 1) sum += __shfl_xor(sum, off, 64);
    float inv = 1.0f / sum;
    P[w][lane]      = e0 * inv;
    P[w][lane + 64] = e1 * inv;
    __syncthreads();

    float a0 = 0.f, a1 = 0.f, a2 = 0.f, a3 = 0.f;
    int d = tid;
#pragma unroll 1
    for (int ki = 0; ki < 32; ++ki) {
        const float* vsrc = m_out_b + ((size_t)b * 16384 + blks[ki]) * 1024;
#pragma unroll
        for (int p = 0; p < 4; ++p) {
            float vv = vsrc[p * 256 + d];
            int n = ki * 4 + p;
            a0 += P[0][n] * vv; a1 += P[1][n] * vv;
            a2 += P[2][n] * vv; a3 += P[3][n] * vv;
        }
    }
    size_t base = (((size_t)b * 256 + d) * 64 + hb * 2) * 64 + wb * 2;
    out[base]      = a0;
    out[base + 1]  = a1;
    out[base + 64] = a2;
    out[base + 65] = a3;
}

extern "C" void kernel_launch(void* const* d_in, const int* in_sizes, int n_in,
                              void* d_out, int out_size, void* d_ws, size_t ws_size,
                              hipStream_t stream) {
    const float* m_in  = (const float*)d_in[0];
    const float* m_out = (const float*)d_in[1];
    const float* q_in  = (const float*)d_in[2];
    const float* qk    = (const float*)d_in[3];

    char* ws = (char*)d_ws;
    float* qk_T    = (float*)(ws);
    float* m_out_b = (float*)(ws);                 // reuses qk_T region (stream-ordered)
    float* m_in_b  = (float*)(ws + 134217728);
    float* q_b     = (float*)(ws + 201326592);
    int*   idxs    = (int*)  (ws + 205520896);

    float* out     = (float*)d_out;
    float* out_mem = out;
    float* out_idx = out + 2097152;
    float* out_val = out + 2113536;

    transpose_qk<<<dim3(256, 16, 2), 256, 0, stream>>>(qk, qk_T);
    topk_kernel<<<2048, 512, 0, stream>>>(qk_T, out_idx, out_val, idxs);
    blockify_tiled<128, 16><<<2 * 16 * 32 * 2, 256, 0, stream>>>(m_in, m_in_b);
    blockify_tiled<128, 1><<<2 * 1 * 32 * 2, 256, 0, stream>>>(q_in, q_b);
    blockify_tiled<256, 16><<<2 * 16 * 32 * 4, 256, 0, stream>>>(m_out, m_out_b);
    attn_kernel<<<2048, 256, 0, stream>>>(m_in_b, m_out_b, q_b, idxs, out_mem);
}